// Round 3
// baseline (471.640 us; speedup 1.0000x reference)
//
#include <hip/hip_runtime.h>
#include <hip/hip_bf16.h>
#include <stdint.h>

// ---------------------------------------------------------------------------
// Decoder (teacher-forced, state never advances):
//   gates = x @ W_ih^T + (h0 @ W_hh^T + b_ih + b_hh)  (broadcast over t)
//   i,f,g,o = split(gates); c' = sig(f)*c0 + sig(i)*tanh(g); h' = sig(o)*tanh(c')
//   out = h' @ fc_w^T + fc_b
// Sizes: B=64, T=1024, D=513, H=512, 4H=2048.  M = B*T = 65536.
// R2: fragment-ordered LDS subtiles ([kq][row][16B] -> reads are base+l*16,
//     conflict-free by construction), per-wave tile 128x64 (32 MFMA / 12
//     ds_read per kstep), BM=256, double-buffered, XCD swizzle kept.
// ---------------------------------------------------------------------------

typedef __bf16 bf16x8 __attribute__((ext_vector_type(8)));
typedef float f32x4 __attribute__((ext_vector_type(4)));

#define MFMA_BF16 __builtin_amdgcn_mfma_f32_16x16x32_bf16

// async global->LDS, 16B per lane. LDS dest must be wave-uniform; HW adds lane*16.
__device__ __forceinline__ void gld16(const void* gptr, void* lptr) {
  __builtin_amdgcn_global_load_lds(
      (const __attribute__((address_space(1))) void*)gptr,
      (__attribute__((address_space(3))) void*)lptr, 16, 0, 0);
}

__device__ __forceinline__ float fsigm(float x) {
  x = fminf(fmaxf(x, -30.f), 30.f);
  return __frcp_rn(1.f + __expf(-x));
}
__device__ __forceinline__ float ftanh(float x) {
  x = fminf(fmaxf(x, -15.f), 15.f);
  const float e = __expf(2.f * x);
  return (e - 1.f) * __frcp_rn(e + 1.f);
}

// --------------------------- pack fp32 -> bf16 ------------------------------
__global__ void pack_bf16_kernel(const float* __restrict__ in,
                                 __bf16* __restrict__ out,
                                 int rows_in, int kin, int kout) {
  const int r = blockIdx.x;
  const bool rv = r < rows_in;
  for (int c = threadIdx.x * 2; c < kout; c += 512) {
    float v0 = (rv && c < kin) ? in[(size_t)r * kin + c] : 0.f;
    float v1 = (rv && c + 1 < kin) ? in[(size_t)r * kin + c + 1] : 0.f;
    union { __bf16 h[2]; uint32_t u; } p;
    p.h[0] = (__bf16)v0;
    p.h[1] = (__bf16)v1;
    *(uint32_t*)&out[(size_t)r * kout + c] = p.u;
  }
}

// --------------------------- hbias ------------------------------------------
__global__ void hbias_kernel(const float* __restrict__ h0,
                             const float* __restrict__ Whh,
                             const float* __restrict__ bih,
                             const float* __restrict__ bhh,
                             float* __restrict__ hbias) {
  const int t = threadIdx.x, w = t >> 6, l = t & 63;
  const int b = blockIdx.x >> 9;
  const int g = ((blockIdx.x & 511) << 2) | w;
  const float* hr = h0 + b * 512;
  const float* wr = Whh + (size_t)g * 512;
  float s = 0.f;
#pragma unroll
  for (int h = 0; h < 512; h += 64) s = fmaf(hr[h + l], wr[h + l], s);
#pragma unroll
  for (int off = 32; off; off >>= 1) s += __shfl_down(s, off);
  if (l == 0) hbias[b * 2048 + g] = s + bih[g] + bhh[g];
}

// --------------------------- GEMM1 + LSTM cell ------------------------------
// BM=256 rows x BN=128 (32 h-cols x 4 gates), BK=32, K=544 (17 ksteps).
// 4 waves as 2M x 2N: wave tile = 128 rows x (4 gates x 16 h-cols).
// LDS: A = 16 subtiles, B = 8 subtiles; subtile = 16 rows x 32 k stored
// fragment-ordered [kq][row][16B] so frag read = subtile_base + lane*16.
__global__ __launch_bounds__(256, 2) void gemm1_kernel(
    const __bf16* __restrict__ xbf, const __bf16* __restrict__ wbf,
    const float* __restrict__ hbias, const float* __restrict__ c0,
    __bf16* __restrict__ hnew) {
  const int t = threadIdx.x;
  const int w = t >> 6, l = t & 63;
  const int wr = w >> 1, wc = w & 1;
  const int lrow = l & 15, lkq = l >> 4;

  // XCD swizzle: 4096 blocks; 16 consecutive swz share one A panel.
  const int bid = blockIdx.x;
  const int swz = (bid & 7) * 512 + (bid >> 3);
  const size_t m0 = (size_t)(swz >> 4) << 8;
  const int n0 = (swz & 15) << 5;

  __shared__ __align__(16) char As[2][16384];
  __shared__ __align__(16) char Bs[2][8192];

  f32x4 acc[8][4];
#pragma unroll
  for (int mi = 0; mi < 8; ++mi)
#pragma unroll
    for (int j = 0; j < 4; ++j) acc[mi][j] = (f32x4){0.f, 0.f, 0.f, 0.f};

  // staging sources: wave w stages A-subtiles {w,w+4,w+8,w+12}, B {w,w+4}.
  // lane l -> row (l&15), k-chunk (l>>4) of the subtile.
  const __bf16* ag = xbf + (m0 + w * 16 + lrow) * 544 + lkq * 8;
  const int brow = (w >> 1) * 512 + n0 + (w & 1) * 16 + lrow;
  const __bf16* bg = wbf + (size_t)brow * 544 + lkq * 8;
  const int aofs = w << 10;   // A subtile w dest; +4096 per extra subtile
  const int bofs = w << 10;

  // prologue: stage kt=0 into buffer 0
  {
    char* ab = As[0];
    char* bb = Bs[0];
#pragma unroll
    for (int i = 0; i < 4; ++i) gld16(ag + i * (64 * 544), ab + aofs + i * 4096);
    gld16(bg, bb + bofs);
    gld16(bg + 1024 * 544, bb + bofs + 4096);
  }
  __syncthreads();

  for (int kt = 0; kt < 17; ++kt) {
    const int bi = kt & 1;
    if (kt < 16) {  // stage next tile into other buffer (overlaps compute)
      const int kof = (kt + 1) << 5;
      char* ab = As[bi ^ 1];
      char* bb = Bs[bi ^ 1];
#pragma unroll
      for (int i = 0; i < 4; ++i)
        gld16(ag + kof + i * (64 * 544), ab + aofs + i * 4096);
      gld16(bg + kof, bb + bofs);
      gld16(bg + kof + 1024 * 544, bb + bofs + 4096);
    }
    const char* ab = As[bi];
    const char* bb = Bs[bi];
    bf16x8 af[8], bfr[4];
#pragma unroll
    for (int mi = 0; mi < 8; ++mi)
      af[mi] = *(const bf16x8*)(ab + (wr * 8 + mi) * 1024 + l * 16);
#pragma unroll
    for (int j = 0; j < 4; ++j)
      bfr[j] = *(const bf16x8*)(bb + (j * 2 + wc) * 1024 + l * 16);
#pragma unroll
    for (int mi = 0; mi < 8; ++mi)
#pragma unroll
      for (int j = 0; j < 4; ++j)
        acc[mi][j] = MFMA_BF16(af[mi], bfr[j], acc[mi][j], 0, 0, 0);
    __syncthreads();  // drains vmcnt(0): next tile landed; LDS reads done
  }

  // epilogue: LSTM cell. C/D: col = lane&15 (h), row = lkq*4 + r (m offset).
  const int h = n0 + wc * 16 + lrow;
  const int b = (int)(m0 >> 10);
  const float hb0 = hbias[b * 2048 + h];
  const float hb1 = hbias[b * 2048 + 512 + h];
  const float hb2 = hbias[b * 2048 + 1024 + h];
  const float hb3 = hbias[b * 2048 + 1536 + h];
  const float c0v = c0[b * 512 + h];
#pragma unroll
  for (int mi = 0; mi < 8; ++mi) {
#pragma unroll
    for (int r = 0; r < 4; ++r) {
      const size_t m = m0 + wr * 128 + mi * 16 + lkq * 4 + r;
      const float gi = acc[mi][0][r] + hb0;
      const float gf = acc[mi][1][r] + hb1;
      const float gg = acc[mi][2][r] + hb2;
      const float go = acc[mi][3][r] + hb3;
      const float cn = fsigm(gf) * c0v + fsigm(gi) * ftanh(gg);
      hnew[m * 512 + h] = (__bf16)(fsigm(go) * ftanh(cn));
    }
  }
}

// --------------------------- GEMM2 + bias -----------------------------------
// BM=256, BN=128, BK=32, K=512 (16 ksteps). fcw padded to 640 rows.
__global__ __launch_bounds__(256, 2) void gemm2_kernel(
    const __bf16* __restrict__ hnew, const __bf16* __restrict__ fcw,
    const float* __restrict__ fcb, float* __restrict__ out) {
  const int t = threadIdx.x;
  const int w = t >> 6, l = t & 63;
  const int wr = w >> 1, wc = w & 1;
  const int lrow = l & 15, lkq = l >> 4;

  const int bid = blockIdx.x;                        // 1280 % 8 == 0
  const int swz = (bid & 7) * 160 + (bid >> 3);
  const size_t m0 = (size_t)(swz / 5) << 8;
  const int n0 = (swz % 5) << 7;

  __shared__ __align__(16) char As[2][16384];
  __shared__ __align__(16) char Bs[2][8192];

  f32x4 acc[8][4];
#pragma unroll
  for (int mi = 0; mi < 8; ++mi)
#pragma unroll
    for (int ni = 0; ni < 4; ++ni) acc[mi][ni] = (f32x4){0.f, 0.f, 0.f, 0.f};

  const __bf16* ag = hnew + (m0 + w * 16 + lrow) * 512 + lkq * 8;
  const __bf16* bg = fcw + (size_t)(n0 + w * 16 + lrow) * 512 + lkq * 8;
  const int aofs = w << 10;
  const int bofs = w << 10;

  {
    char* ab = As[0];
    char* bb = Bs[0];
#pragma unroll
    for (int i = 0; i < 4; ++i) gld16(ag + i * (64 * 512), ab + aofs + i * 4096);
    gld16(bg, bb + bofs);
    gld16(bg + 64 * 512, bb + bofs + 4096);
  }
  __syncthreads();

  for (int kt = 0; kt < 16; ++kt) {
    const int bi = kt & 1;
    if (kt < 15) {
      const int kof = (kt + 1) << 5;
      char* ab = As[bi ^ 1];
      char* bb = Bs[bi ^ 1];
#pragma unroll
      for (int i = 0; i < 4; ++i)
        gld16(ag + kof + i * (64 * 512), ab + aofs + i * 4096);
      gld16(bg + kof, bb + bofs);
      gld16(bg + kof + 64 * 512, bb + bofs + 4096);
    }
    const char* ab = As[bi];
    const char* bb = Bs[bi];
    bf16x8 af[8], bfr[4];
#pragma unroll
    for (int mi = 0; mi < 8; ++mi)
      af[mi] = *(const bf16x8*)(ab + (wr * 8 + mi) * 1024 + l * 16);
#pragma unroll
    for (int ni = 0; ni < 4; ++ni)
      bfr[ni] = *(const bf16x8*)(bb + (wc * 4 + ni) * 1024 + l * 16);
#pragma unroll
    for (int mi = 0; mi < 8; ++mi)
#pragma unroll
      for (int ni = 0; ni < 4; ++ni)
        acc[mi][ni] = MFMA_BF16(af[mi], bfr[ni], acc[mi][ni], 0, 0, 0);
    __syncthreads();
  }

#pragma unroll
  for (int ni = 0; ni < 4; ++ni) {
    const int n = n0 + wc * 64 + ni * 16 + lrow;
    if (n < 513) {
      const float bias = fcb[n];
#pragma unroll
      for (int mi = 0; mi < 8; ++mi) {
#pragma unroll
        for (int r = 0; r < 4; ++r) {
          const size_t m = m0 + wr * 128 + mi * 16 + lkq * 4 + r;
          out[m * 513 + n] = acc[mi][ni][r] + bias;
        }
      }
    }
  }
}

// --------------------------- launch -----------------------------------------
extern "C" void kernel_launch(void* const* d_in, const int* in_sizes, int n_in,
                              void* d_out, int out_size, void* d_ws, size_t ws_size,
                              hipStream_t stream) {
  const float* x = (const float*)d_in[0];     // [64,1024,513]
  const float* h0 = (const float*)d_in[1];    // [1,64,512]
  const float* c0 = (const float*)d_in[2];    // [1,64,512]
  const float* Wih = (const float*)d_in[3];   // [2048,513]
  const float* Whh = (const float*)d_in[4];   // [2048,512]
  const float* bih = (const float*)d_in[5];   // [2048]
  const float* bhh = (const float*)d_in[6];   // [2048]
  const float* fcw = (const float*)d_in[7];   // [513,512]
  const float* fcb = (const float*)d_in[8];   // [513]
  float* out = (float*)d_out;                 // [64,1024,513]

  char* ws = (char*)d_ws;
  __bf16* xbf = (__bf16*)(ws);                       // 65536*544*2 = 71,303,168
  __bf16* wbf = (__bf16*)(ws + 71303168);            //  2048*544*2 =  2,228,224
  __bf16* fwbf = (__bf16*)(ws + 73531392);           //   640*512*2 =    655,360
  float* hb = (float*)(ws + 74186752);               //   64*2048*4 =    524,288
  __bf16* hn = (__bf16*)(ws + 74711040);             // 65536*512*2 = 67,108,864

  pack_bf16_kernel<<<65536, 256, 0, stream>>>(x, xbf, 65536, 513, 544);
  pack_bf16_kernel<<<2048, 256, 0, stream>>>(Wih, wbf, 2048, 513, 544);
  pack_bf16_kernel<<<640, 256, 0, stream>>>(fcw, fwbf, 513, 512, 512);
  hbias_kernel<<<32768, 256, 0, stream>>>(h0, Whh, bih, bhh, hb);
  gemm1_kernel<<<4096, 256, 0, stream>>>(xbf, wbf, hb, c0, hn);
  gemm2_kernel<<<dim3(1280), 256, 0, stream>>>(hn, fwbf, fcb, out);
}

// Round 4
// 440.300 us; speedup vs baseline: 1.0712x; 1.0712x over previous
//
#include <hip/hip_runtime.h>
#include <hip/hip_bf16.h>
#include <stdint.h>

// ---------------------------------------------------------------------------
// Decoder (teacher-forced, state never advances):
//   gates = x @ W_ih^T + (h0 @ W_hh^T + b_ih + b_hh)  (broadcast over t)
//   i,f,g,o = split(gates); c' = sig(f)*c0 + sig(i)*tanh(g); h' = sig(o)*tanh(c')
//   out = h' @ fc_w^T + fc_b
// Sizes: B=64, T=1024, D=513, H=512, 4H=2048.  M = B*T = 65536.
// R3: 256x256 8-phase schedule (T3+T4+T5), BK=64, 512 thr / 8 waves (2Mx4N),
//     128KB LDS double-buffer, fragment-ordered subtiles (identity ds_read),
//     counted vmcnt(4) gates (never 0 in steady state), gate-interleaved W
//     packing so the LSTM epilogue stays lane-local. gemm2 same template.
// ---------------------------------------------------------------------------

typedef __bf16 bf16x8 __attribute__((ext_vector_type(8)));
typedef float f32x4 __attribute__((ext_vector_type(4)));

#define MFMA_BF16 __builtin_amdgcn_mfma_f32_16x16x32_bf16

__device__ __forceinline__ void gld16(const void* gptr, void* lptr) {
  __builtin_amdgcn_global_load_lds(
      (const __attribute__((address_space(1))) void*)gptr,
      (__attribute__((address_space(3))) void*)lptr, 16, 0, 0);
}

__device__ __forceinline__ float fsigm(float x) {
  x = fminf(fmaxf(x, -30.f), 30.f);
  return __frcp_rn(1.f + __expf(-x));
}
__device__ __forceinline__ float ftanh(float x) {
  x = fminf(fmaxf(x, -15.f), 15.f);
  const float e = __expf(2.f * x);
  return (e - 1.f) * __frcp_rn(e + 1.f);
}

// --------------------------- pack fp32 -> bf16 ------------------------------
__global__ void pack_bf16_kernel(const float* __restrict__ in,
                                 __bf16* __restrict__ out,
                                 int rows_in, int kin, int kout) {
  const int r = blockIdx.x;
  const bool rv = r < rows_in;
  for (int c = threadIdx.x * 2; c < kout; c += 512) {
    float v0 = (rv && c < kin) ? in[(size_t)r * kin + c] : 0.f;
    float v1 = (rv && c + 1 < kin) ? in[(size_t)r * kin + c + 1] : 0.f;
    union { __bf16 h[2]; uint32_t u; } p;
    p.h[0] = (__bf16)v0;
    p.h[1] = (__bf16)v1;
    *(uint32_t*)&out[(size_t)r * kout + c] = p.u;
  }
}

// pack W_ih gate-interleaved: packed row p -> gate (p>>4)&3, h (p>>6)*16+(p&15)
__global__ void pack_wih_kernel(const float* __restrict__ Wih,
                                __bf16* __restrict__ wpk) {
  const int p = blockIdx.x;  // 0..2047
  const int g = (p >> 4) & 3;
  const int h = ((p >> 6) << 4) + (p & 15);
  const float* src = Wih + (size_t)(g * 512 + h) * 513;
  for (int c = threadIdx.x * 2; c < 576; c += 512) {
    float v0 = (c < 513) ? src[c] : 0.f;
    float v1 = (c + 1 < 513) ? src[c + 1] : 0.f;
    union { __bf16 hh[2]; uint32_t u; } pk;
    pk.hh[0] = (__bf16)v0;
    pk.hh[1] = (__bf16)v1;
    *(uint32_t*)&wpk[(size_t)p * 576 + c] = pk.u;
  }
}

// --------------------------- hbias ------------------------------------------
__global__ void hbias_kernel(const float* __restrict__ h0,
                             const float* __restrict__ Whh,
                             const float* __restrict__ bih,
                             const float* __restrict__ bhh,
                             float* __restrict__ hbias) {
  const int t = threadIdx.x, w = t >> 6, l = t & 63;
  const int b = blockIdx.x >> 9;
  const int g = ((blockIdx.x & 511) << 2) | w;
  const float* hr = h0 + b * 512;
  const float* wr = Whh + (size_t)g * 512;
  float s = 0.f;
#pragma unroll
  for (int h = 0; h < 512; h += 64) s = fmaf(hr[h + l], wr[h + l], s);
#pragma unroll
  for (int off = 32; off; off >>= 1) s += __shfl_down(s, off);
  if (l == 0) hbias[b * 2048 + g] = s + bih[g] + bhh[g];
}

// --------------------------- 8-phase GEMM core ------------------------------
// Tile 256x256, BK=64, 8 waves (2M x 4N), per-wave 128x64 (acc[8][4]).
// LDS per buffer: A 32KB (2 halves x 16 subtiles x 1KB) + B 32KB; 2 buffers.
// Subtile = 16 rows x 32 k, fragment-ordered: lane l <-> (row l&15, kq l>>4),
// so both the gld16 write and the ds_read are identity (base + l*16).
// Per K-tile: 4 phases (ks,mh); phase stages one quarter of K-tile kt+1:
//   q0: A-k0, q1: B-k0, q2: A-k1, q3: B-k1  (2 gld16 each)
// vmcnt(4) after MFMA at q1 (gates this tile's k1 quarters, staged prev q2/q3)
// and q3 (gates next tile's k0 quarters, staged this q0/q1). Tail uses 0.

#define STAGE_A(KT, KS, WB)                                        \
  {                                                                \
    const __bf16* s_ = agp + (KT) * 64 + (KS) * 32;                \
    gld16(s_, ldsb + (WB) + (KS) * 8192 + stA);                    \
    gld16(s_ + 128 * KSTR, ldsb + (WB) + 16384 + (KS) * 8192 + stA); \
  }
#define STAGE_B(KT, KS, WB)                                        \
  {                                                                \
    const __bf16* s_ = bgp + (KT) * 64 + (KS) * 32;                \
    gld16(s_, ldsb + (WB) + 32768 + (KS) * 8192 + stA);            \
    gld16(s_ + 128 * KSTR, ldsb + (WB) + 49152 + (KS) * 8192 + stA); \
  }

#define PH(KS, MH, DOB, STAGE, GATE)                                         \
  {                                                                          \
    const char* rbp_ = ldsb + rb;                                            \
    bf16x8 a0 = *(const bf16x8*)(rbp_ + raA + ((KS) * 8 + (MH) * 4 + 0) * 1024); \
    bf16x8 a1 = *(const bf16x8*)(rbp_ + raA + ((KS) * 8 + (MH) * 4 + 1) * 1024); \
    bf16x8 a2 = *(const bf16x8*)(rbp_ + raA + ((KS) * 8 + (MH) * 4 + 2) * 1024); \
    bf16x8 a3 = *(const bf16x8*)(rbp_ + raA + ((KS) * 8 + (MH) * 4 + 3) * 1024); \
    if (DOB) {                                                               \
      b0 = *(const bf16x8*)(rbp_ + raB + ((KS) * 8 + 0) * 1024);             \
      b1 = *(const bf16x8*)(rbp_ + raB + ((KS) * 8 + 1) * 1024);             \
      b2 = *(const bf16x8*)(rbp_ + raB + ((KS) * 8 + 2) * 1024);             \
      b3 = *(const bf16x8*)(rbp_ + raB + ((KS) * 8 + 3) * 1024);             \
    }                                                                        \
    STAGE;                                                                   \
    asm volatile("" ::: "memory");                                          \
    __builtin_amdgcn_s_barrier();                                            \
    __builtin_amdgcn_sched_barrier(0);                                       \
    __builtin_amdgcn_s_setprio(1);                                           \
    acc[(MH) * 4 + 0][0] = MFMA_BF16(a0, b0, acc[(MH) * 4 + 0][0], 0, 0, 0); \
    acc[(MH) * 4 + 0][1] = MFMA_BF16(a0, b1, acc[(MH) * 4 + 0][1], 0, 0, 0); \
    acc[(MH) * 4 + 0][2] = MFMA_BF16(a0, b2, acc[(MH) * 4 + 0][2], 0, 0, 0); \
    acc[(MH) * 4 + 0][3] = MFMA_BF16(a0, b3, acc[(MH) * 4 + 0][3], 0, 0, 0); \
    acc[(MH) * 4 + 1][0] = MFMA_BF16(a1, b0, acc[(MH) * 4 + 1][0], 0, 0, 0); \
    acc[(MH) * 4 + 1][1] = MFMA_BF16(a1, b1, acc[(MH) * 4 + 1][1], 0, 0, 0); \
    acc[(MH) * 4 + 1][2] = MFMA_BF16(a1, b2, acc[(MH) * 4 + 1][2], 0, 0, 0); \
    acc[(MH) * 4 + 1][3] = MFMA_BF16(a1, b3, acc[(MH) * 4 + 1][3], 0, 0, 0); \
    acc[(MH) * 4 + 2][0] = MFMA_BF16(a2, b0, acc[(MH) * 4 + 2][0], 0, 0, 0); \
    acc[(MH) * 4 + 2][1] = MFMA_BF16(a2, b1, acc[(MH) * 4 + 2][1], 0, 0, 0); \
    acc[(MH) * 4 + 2][2] = MFMA_BF16(a2, b2, acc[(MH) * 4 + 2][2], 0, 0, 0); \
    acc[(MH) * 4 + 2][3] = MFMA_BF16(a2, b3, acc[(MH) * 4 + 2][3], 0, 0, 0); \
    acc[(MH) * 4 + 3][0] = MFMA_BF16(a3, b0, acc[(MH) * 4 + 3][0], 0, 0, 0); \
    acc[(MH) * 4 + 3][1] = MFMA_BF16(a3, b1, acc[(MH) * 4 + 3][1], 0, 0, 0); \
    acc[(MH) * 4 + 3][2] = MFMA_BF16(a3, b2, acc[(MH) * 4 + 3][2], 0, 0, 0); \
    acc[(MH) * 4 + 3][3] = MFMA_BF16(a3, b3, acc[(MH) * 4 + 3][3], 0, 0, 0); \
    __builtin_amdgcn_s_setprio(0);                                           \
    GATE;                                                                    \
    asm volatile("" ::: "memory");                                          \
    __builtin_amdgcn_s_barrier();                                            \
    asm volatile("" ::: "memory");                                          \
  }

template <int NKT, int KSTR>
__device__ __forceinline__ void gemm_core(
    const __bf16* __restrict__ Asrc, const __bf16* __restrict__ Bsrc,
    size_t m0, int n0, char* ldsb, f32x4 (&acc)[8][4],
    int wid, int l, int wm, int wn) {
  // staging sources (per lane): row = base + wid*16 + (l&15), k chunk l>>4
  const __bf16* agp = Asrc + (m0 + wid * 16 + (l & 15)) * KSTR + ((l >> 4) << 3);
  const __bf16* bgp = Bsrc + (size_t)(n0 + wid * 16 + (l & 15)) * KSTR + ((l >> 4) << 3);
  const int stA = wid << 10;  // wave-uniform LDS dest within quarter

  // read bases (identity fragment reads)
  const int raA = (wm << 14) + l * 16;
  const int raB = 32768 + ((wn >> 1) << 14) + ((wn & 1) << 12) + l * 16;

  bf16x8 b0{}, b1{}, b2{}, b3{};

  // prologue: stage all 4 quarters of K-tile 0 into buffer 0
  STAGE_A(0, 0, 0);
  STAGE_B(0, 0, 0);
  STAGE_A(0, 1, 0);
  STAGE_B(0, 1, 0);
  asm volatile("s_waitcnt vmcnt(0)" ::: "memory");
  __builtin_amdgcn_s_barrier();
  asm volatile("" ::: "memory");

  for (int kt = 0; kt < NKT; ++kt) {
    const int rb = (kt & 1) << 16;
    const int wb = rb ^ 65536;
    const bool more = (kt + 1) < NKT;
    PH(0, 0, 1, if (more) STAGE_A(kt + 1, 0, wb), );
    PH(0, 1, 0, if (more) STAGE_B(kt + 1, 0, wb),
       if (more) { asm volatile("s_waitcnt vmcnt(4)" ::: "memory"); }
       else { asm volatile("s_waitcnt vmcnt(0)" ::: "memory"); });
    PH(1, 0, 1, if (more) STAGE_A(kt + 1, 1, wb), );
    PH(1, 1, 0, if (more) STAGE_B(kt + 1, 1, wb),
       if (more) { asm volatile("s_waitcnt vmcnt(4)" ::: "memory"); });
  }
}

// --------------------------- GEMM1 + LSTM cell ------------------------------
__global__ __launch_bounds__(512, 2) void gemm1_kernel(
    const __bf16* __restrict__ xbf, const __bf16* __restrict__ wpk,
    const float* __restrict__ hbias, const float* __restrict__ c0,
    __bf16* __restrict__ hnew) {
  const int t = threadIdx.x, wid = t >> 6, l = t & 63;
  const int wm = wid >> 2, wn = wid & 3;
  const int bid = blockIdx.x;  // 2048 blocks
  const int swz = (bid & 7) * 256 + (bid >> 3);
  const int nt = swz & 7;
  const size_t m0 = (size_t)(swz >> 3) << 8;
  const int n0 = nt << 8;

  __shared__ __align__(16) char lds[131072];
  char* ldsb = lds;

  f32x4 acc[8][4];
#pragma unroll
  for (int mi = 0; mi < 8; ++mi)
#pragma unroll
    for (int ni = 0; ni < 4; ++ni) acc[mi][ni] = (f32x4){0.f, 0.f, 0.f, 0.f};

  gemm_core<9, 576>(xbf, wpk, m0, n0, ldsb, acc, wid, l, wm, wn);

  // epilogue: lane's column p = n0 + wn*64 + ni*16 + (l&15)
  //   -> gate = ni, h = (nt*4 + wn)*16 + (l&15)
  const int hcol = ((nt * 4 + wn) << 4) + (l & 15);
  const int b = (int)(m0 >> 10);
  const float hb0 = hbias[b * 2048 + hcol];
  const float hb1 = hbias[b * 2048 + 512 + hcol];
  const float hb2 = hbias[b * 2048 + 1024 + hcol];
  const float hb3 = hbias[b * 2048 + 1536 + hcol];
  const float c0v = c0[b * 512 + hcol];
  const int mrow = (l >> 4) << 2;
#pragma unroll
  for (int mi = 0; mi < 8; ++mi) {
#pragma unroll
    for (int r = 0; r < 4; ++r) {
      const size_t m = m0 + wm * 128 + mi * 16 + mrow + r;
      const float gi = acc[mi][0][r] + hb0;
      const float gf = acc[mi][1][r] + hb1;
      const float gg = acc[mi][2][r] + hb2;
      const float go = acc[mi][3][r] + hb3;
      const float cn = fsigm(gf) * c0v + fsigm(gi) * ftanh(gg);
      hnew[m * 512 + hcol] = (__bf16)(fsigm(go) * ftanh(cn));
    }
  }
}

// --------------------------- GEMM2 + bias -----------------------------------
__global__ __launch_bounds__(512, 2) void gemm2_kernel(
    const __bf16* __restrict__ hnew, const __bf16* __restrict__ fcw,
    const float* __restrict__ fcb, float* __restrict__ out) {
  const int t = threadIdx.x, wid = t >> 6, l = t & 63;
  const int wm = wid >> 2, wn = wid & 3;
  const int bid = blockIdx.x;  // 768 blocks
  const int swz = (bid & 7) * 96 + (bid >> 3);
  const int nt = swz % 3;
  const size_t m0 = (size_t)(swz / 3) << 8;
  const int n0 = nt << 8;

  __shared__ __align__(16) char lds[131072];
  char* ldsb = lds;

  f32x4 acc[8][4];
#pragma unroll
  for (int mi = 0; mi < 8; ++mi)
#pragma unroll
    for (int ni = 0; ni < 4; ++ni) acc[mi][ni] = (f32x4){0.f, 0.f, 0.f, 0.f};

  gemm_core<8, 512>(hnew, fcw, m0, n0, ldsb, acc, wid, l, wm, wn);

  const int mrow = (l >> 4) << 2;
#pragma unroll
  for (int ni = 0; ni < 4; ++ni) {
    const int n = n0 + wn * 64 + ni * 16 + (l & 15);
    if (n < 513) {
      const float bias = fcb[n];
#pragma unroll
      for (int mi = 0; mi < 8; ++mi) {
#pragma unroll
        for (int r = 0; r < 4; ++r) {
          const size_t m = m0 + wm * 128 + mi * 16 + mrow + r;
          out[m * 513 + n] = acc[mi][ni][r] + bias;
        }
      }
    }
  }
}

// --------------------------- launch -----------------------------------------
extern "C" void kernel_launch(void* const* d_in, const int* in_sizes, int n_in,
                              void* d_out, int out_size, void* d_ws, size_t ws_size,
                              hipStream_t stream) {
  const float* x = (const float*)d_in[0];     // [64,1024,513]
  const float* h0 = (const float*)d_in[1];    // [1,64,512]
  const float* c0 = (const float*)d_in[2];    // [1,64,512]
  const float* Wih = (const float*)d_in[3];   // [2048,513]
  const float* Whh = (const float*)d_in[4];   // [2048,512]
  const float* bih = (const float*)d_in[5];   // [2048]
  const float* bhh = (const float*)d_in[6];   // [2048]
  const float* fcw = (const float*)d_in[7];   // [513,512]
  const float* fcb = (const float*)d_in[8];   // [513]
  float* out = (float*)d_out;                 // [64,1024,513]

  char* ws = (char*)d_ws;
  __bf16* xbf = (__bf16*)(ws);                 // 65536*576*2 = 75,497,472
  __bf16* wpk = (__bf16*)(ws + 75497472);      //  2048*576*2 =  2,359,296
  __bf16* fwbf = (__bf16*)(ws + 77856768);     //   768*512*2 =    786,432
  float* hb = (float*)(ws + 78643200);         //   64*2048*4 =    524,288
  __bf16* hn = (__bf16*)(ws + 79167488);       // 65536*512*2 = 67,108,864
  // total ws use: 146,276,352 bytes

  pack_bf16_kernel<<<65536, 256, 0, stream>>>(x, xbf, 65536, 513, 576);
  pack_wih_kernel<<<2048, 256, 0, stream>>>(Wih, wpk);
  pack_bf16_kernel<<<768, 256, 0, stream>>>(fcw, fwbf, 513, 512, 512);
  hbias_kernel<<<32768, 256, 0, stream>>>(h0, Whh, bih, bhh, hb);
  gemm1_kernel<<<2048, 512, 0, stream>>>(xbf, wpk, hb, c0, hn);
  gemm2_kernel<<<768, 512, 0, stream>>>(hn, fwbf, fcb, out);
}

// Round 5
// 388.662 us; speedup vs baseline: 1.2135x; 1.1329x over previous
//
#include <hip/hip_runtime.h>
#include <hip/hip_bf16.h>
#include <stdint.h>

// ---------------------------------------------------------------------------
// Decoder (teacher-forced, state never advances):
//   gates = x @ W_ih^T + (h0 @ W_hh^T + b_ih + b_hh)  (broadcast over t)
//   i,f,g,o = split(gates); c' = sig(f)*c0 + sig(i)*tanh(g); h' = sig(o)*tanh(c')
//   out = h' @ fc_w^T + fc_b
// Sizes: B=64, T=1024, D=513, H=512, 4H=2048.  M = B*T = 65536.
// R4: 128x128 tile, 4 waves (2Mx2N), BK=32, TRIPLE-buffered LDS (48KB ->
//     3 blocks/CU) staging 2 K-tiles ahead; ONE barrier + one counted
//     vmcnt(4) per K-tile (never 0 in steady state); fragment-ordered
//     0-conflict LDS; setprio around MFMA cluster; XCD swizzle;
//     gate-interleaved W so LSTM epilogue is lane-local.
// ---------------------------------------------------------------------------

typedef __bf16 bf16x8 __attribute__((ext_vector_type(8)));
typedef float f32x4 __attribute__((ext_vector_type(4)));

#define MFMA_BF16 __builtin_amdgcn_mfma_f32_16x16x32_bf16

__device__ __forceinline__ void gld16(const void* gptr, void* lptr) {
  __builtin_amdgcn_global_load_lds(
      (const __attribute__((address_space(1))) void*)gptr,
      (__attribute__((address_space(3))) void*)lptr, 16, 0, 0);
}

__device__ __forceinline__ float fsigm(float x) {
  x = fminf(fmaxf(x, -30.f), 30.f);
  return __frcp_rn(1.f + __expf(-x));
}
__device__ __forceinline__ float ftanh(float x) {
  x = fminf(fmaxf(x, -15.f), 15.f);
  const float e = __expf(2.f * x);
  return (e - 1.f) * __frcp_rn(e + 1.f);
}

// --------------------------- pack fp32 -> bf16 ------------------------------
__global__ void pack_bf16_kernel(const float* __restrict__ in,
                                 __bf16* __restrict__ out,
                                 int rows_in, int kin, int kout) {
  const int r = blockIdx.x;
  const bool rv = r < rows_in;
  for (int c = threadIdx.x * 2; c < kout; c += 512) {
    float v0 = (rv && c < kin) ? in[(size_t)r * kin + c] : 0.f;
    float v1 = (rv && c + 1 < kin) ? in[(size_t)r * kin + c + 1] : 0.f;
    union { __bf16 h[2]; uint32_t u; } p;
    p.h[0] = (__bf16)v0;
    p.h[1] = (__bf16)v1;
    *(uint32_t*)&out[(size_t)r * kout + c] = p.u;
  }
}

// pack W_ih gate-interleaved: packed row p -> gate (p>>4)&3, h (p>>6)*16+(p&15)
__global__ void pack_wih_kernel(const float* __restrict__ Wih,
                                __bf16* __restrict__ wpk) {
  const int p = blockIdx.x;  // 0..2047
  const int g = (p >> 4) & 3;
  const int h = ((p >> 6) << 4) + (p & 15);
  const float* src = Wih + (size_t)(g * 512 + h) * 513;
  for (int c = threadIdx.x * 2; c < 544; c += 512) {
    float v0 = (c < 513) ? src[c] : 0.f;
    float v1 = (c + 1 < 513) ? src[c + 1] : 0.f;
    union { __bf16 hh[2]; uint32_t u; } pk;
    pk.hh[0] = (__bf16)v0;
    pk.hh[1] = (__bf16)v1;
    *(uint32_t*)&wpk[(size_t)p * 544 + c] = pk.u;
  }
}

// --------------------------- hbias ------------------------------------------
__global__ void hbias_kernel(const float* __restrict__ h0,
                             const float* __restrict__ Whh,
                             const float* __restrict__ bih,
                             const float* __restrict__ bhh,
                             float* __restrict__ hbias) {
  const int t = threadIdx.x, w = t >> 6, l = t & 63;
  const int b = blockIdx.x >> 9;
  const int g = ((blockIdx.x & 511) << 2) | w;
  const float* hr = h0 + b * 512;
  const float* wr = Whh + (size_t)g * 512;
  float s = 0.f;
#pragma unroll
  for (int h = 0; h < 512; h += 64) s = fmaf(hr[h + l], wr[h + l], s);
#pragma unroll
  for (int off = 32; off; off >>= 1) s += __shfl_down(s, off);
  if (l == 0) hbias[b * 2048 + g] = s + bih[g] + bhh[g];
}

// --------------------------- triple-buffer GEMM core ------------------------
// Tile 128x128, BK=32, 4 waves (2M x 2N), per-wave 64x64 (acc[4][4]).
// LDS: 3 buffers x (A 8KB + B 8KB) = 48KB. Tile kt reads buf kt%3 and stages
// tile kt+2 into (kt+2)%3 -> read/write buffers always disjoint; one barrier
// per tile; steady-state gate vmcnt(4) (waits only the tile-(kt+1) stage).
// Subtile = 16 rows x 32 k, fragment-ordered (lane l <-> row l&15, kq l>>4):
// gld16 dest and ds_read are both identity (base + l*16) -> 0 conflicts.
template <int NKT, int KSTR>
__device__ __forceinline__ void gemm_core(
    const __bf16* __restrict__ A, const __bf16* __restrict__ B,
    size_t m0, int n0, char* lds, f32x4 (&acc)[4][4],
    int w, int l, int wm, int wc) {
  const int lr = l & 15, lq = l >> 4;
  // wave w stages A rows [w*32, w*32+32) (subtiles 2w, 2w+1), same for B.
  const __bf16* ag = A + (m0 + w * 32 + lr) * KSTR + lq * 8;
  const __bf16* bg = B + (size_t)(n0 + w * 32 + lr) * KSTR + lq * 8;
  const int sdst = w * 2048;            // wave-uniform LDS dest (2 subtiles)
  const int ra = wm * 4096 + l * 16;    // A read base, + mi*1024
  const int rbB = 8192 + wc * 4096 + l * 16;  // B read base, + ni*1024

  // prologue: stage K-tiles 0 and 1 into buffers 0 and 1
#pragma unroll
  for (int p = 0; p < 2; ++p) {
    char* base = lds + p * 16384;
    gld16(ag + p * 32, base + sdst);
    gld16(ag + p * 32 + 16 * KSTR, base + sdst + 1024);
    gld16(bg + p * 32, base + 8192 + sdst);
    gld16(bg + p * 32 + 16 * KSTR, base + 8192 + sdst + 1024);
  }
  asm volatile("s_waitcnt vmcnt(4)" ::: "memory");  // tile-0 stage landed
  __builtin_amdgcn_s_barrier();

  int rb = 0;
  for (int kt = 0; kt < NKT; ++kt) {
    char* rbase = lds + rb * 16384;
    if (kt + 2 < NKT) {  // stage tile kt+2 into the buffer freed at kt-1
      char* wbase = lds + ((rb + 2) % 3) * 16384;
      const int kof = (kt + 2) * 32;
      gld16(ag + kof, wbase + sdst);
      gld16(ag + kof + 16 * KSTR, wbase + sdst + 1024);
      gld16(bg + kof, wbase + 8192 + sdst);
      gld16(bg + kof + 16 * KSTR, wbase + 8192 + sdst + 1024);
    }
    bf16x8 af[4], bq[4];
#pragma unroll
    for (int i = 0; i < 4; ++i)
      af[i] = *(const bf16x8*)(rbase + ra + i * 1024);
#pragma unroll
    for (int i = 0; i < 4; ++i)
      bq[i] = *(const bf16x8*)(rbase + rbB + i * 1024);
    __builtin_amdgcn_s_setprio(1);
#pragma unroll
    for (int mi = 0; mi < 4; ++mi)
#pragma unroll
      for (int ni = 0; ni < 4; ++ni)
        acc[mi][ni] = MFMA_BF16(af[mi], bq[ni], acc[mi][ni], 0, 0, 0);
    __builtin_amdgcn_s_setprio(0);
    if (kt + 2 < NKT) {
      asm volatile("s_waitcnt vmcnt(4)" ::: "memory");  // tile kt+1 landed
    } else if (kt + 1 < NKT) {
      asm volatile("s_waitcnt vmcnt(0)" ::: "memory");  // tail: last tile
    }
    asm volatile("" ::: "memory");
    __builtin_amdgcn_s_barrier();
    rb = (rb == 2) ? 0 : rb + 1;
  }
}

// --------------------------- GEMM1 + LSTM cell ------------------------------
// A = xbf [65536 x 544], B = wpk [2048 x 544] gate-interleaved.
// grid 8192 = 512 m-tiles x 16 n-tiles.
__global__ __launch_bounds__(256, 3) void gemm1_kernel(
    const __bf16* __restrict__ xbf, const __bf16* __restrict__ wpk,
    const float* __restrict__ hbias, const float* __restrict__ c0,
    __bf16* __restrict__ hnew) {
  const int t = threadIdx.x, w = t >> 6, l = t & 63;
  const int wm = w >> 1, wc = w & 1;
  const int bid = blockIdx.x;
  const int swz = (bid & 7) * 1024 + (bid >> 3);  // XCD-contiguous
  const size_t m0 = (size_t)(swz >> 4) << 7;
  const int n0 = (swz & 15) << 7;

  __shared__ __align__(16) char lds[49152];

  f32x4 acc[4][4];
#pragma unroll
  for (int mi = 0; mi < 4; ++mi)
#pragma unroll
    for (int ni = 0; ni < 4; ++ni) acc[mi][ni] = (f32x4){0.f, 0.f, 0.f, 0.f};

  gemm_core<17, 544>(xbf, wpk, m0, n0, lds, acc, w, l, wm, wc);

  // lane's packed col p = n0 + wc*64 + ni*16 + (l&15) -> gate = ni,
  // h = ((n0>>6) + wc)*16 + (l&15). All 4 gates lane-local.
  const int lr = l & 15, lq = l >> 4;
  const int hcol = (((n0 >> 6) + wc) << 4) + lr;
  const int b = (int)(m0 >> 10);
  const float hb0 = hbias[b * 2048 + hcol];
  const float hb1 = hbias[b * 2048 + 512 + hcol];
  const float hb2 = hbias[b * 2048 + 1024 + hcol];
  const float hb3 = hbias[b * 2048 + 1536 + hcol];
  const float c0v = c0[b * 512 + hcol];
#pragma unroll
  for (int mi = 0; mi < 4; ++mi) {
#pragma unroll
    for (int r = 0; r < 4; ++r) {
      const size_t m = m0 + wm * 64 + mi * 16 + lq * 4 + r;
      const float gi = acc[mi][0][r] + hb0;
      const float gf = acc[mi][1][r] + hb1;
      const float gg = acc[mi][2][r] + hb2;
      const float go = acc[mi][3][r] + hb3;
      const float cn = fsigm(gf) * c0v + fsigm(gi) * ftanh(gg);
      hnew[m * 512 + hcol] = (__bf16)(fsigm(go) * ftanh(cn));
    }
  }
}

// --------------------------- GEMM2 + bias -----------------------------------
// A = hnew [65536 x 512], B = fwbf [640 x 512] (rows 513.. zero).
// grid 2560 = 512 m-tiles x 5 n-tiles.
__global__ __launch_bounds__(256, 3) void gemm2_kernel(
    const __bf16* __restrict__ hnew, const __bf16* __restrict__ fcw,
    const float* __restrict__ fcb, float* __restrict__ out) {
  const int t = threadIdx.x, w = t >> 6, l = t & 63;
  const int wm = w >> 1, wc = w & 1;
  const int bid = blockIdx.x;
  const int swz = (bid & 7) * 320 + (bid >> 3);
  const size_t m0 = (size_t)(swz / 5) << 7;
  const int n0 = (swz % 5) << 7;

  __shared__ __align__(16) char lds[49152];

  f32x4 acc[4][4];
#pragma unroll
  for (int mi = 0; mi < 4; ++mi)
#pragma unroll
    for (int ni = 0; ni < 4; ++ni) acc[mi][ni] = (f32x4){0.f, 0.f, 0.f, 0.f};

  gemm_core<16, 512>(hnew, fcw, m0, n0, lds, acc, w, l, wm, wc);

  const int lr = l & 15, lq = l >> 4;
#pragma unroll
  for (int ni = 0; ni < 4; ++ni) {
    const int n = n0 + wc * 64 + ni * 16 + lr;
    if (n < 513) {
      const float bias = fcb[n];
#pragma unroll
      for (int mi = 0; mi < 4; ++mi) {
#pragma unroll
        for (int r = 0; r < 4; ++r) {
          const size_t m = m0 + wm * 64 + mi * 16 + lq * 4 + r;
          out[m * 513 + n] = acc[mi][ni][r] + bias;
        }
      }
    }
  }
}

// --------------------------- launch -----------------------------------------
extern "C" void kernel_launch(void* const* d_in, const int* in_sizes, int n_in,
                              void* d_out, int out_size, void* d_ws, size_t ws_size,
                              hipStream_t stream) {
  const float* x = (const float*)d_in[0];     // [64,1024,513]
  const float* h0 = (const float*)d_in[1];    // [1,64,512]
  const float* c0 = (const float*)d_in[2];    // [1,64,512]
  const float* Wih = (const float*)d_in[3];   // [2048,513]
  const float* Whh = (const float*)d_in[4];   // [2048,512]
  const float* bih = (const float*)d_in[5];   // [2048]
  const float* bhh = (const float*)d_in[6];   // [2048]
  const float* fcw = (const float*)d_in[7];   // [513,512]
  const float* fcb = (const float*)d_in[8];   // [513]
  float* out = (float*)d_out;                 // [64,1024,513]

  char* ws = (char*)d_ws;
  __bf16* xbf = (__bf16*)(ws);                 // 65536*544*2 = 71,303,168
  __bf16* wpk = (__bf16*)(ws + 71303168);      //  2048*544*2 =  2,228,224
  __bf16* fwbf = (__bf16*)(ws + 73531392);     //   640*512*2 =    655,360
  float* hb = (float*)(ws + 74186752);         //   64*2048*4 =    524,288
  __bf16* hn = (__bf16*)(ws + 74711040);       // 65536*512*2 = 67,108,864
  // total ws use: 141,819,904 bytes

  pack_bf16_kernel<<<65536, 256, 0, stream>>>(x, xbf, 65536, 513, 544);
  pack_wih_kernel<<<2048, 256, 0, stream>>>(Wih, wpk);
  pack_bf16_kernel<<<640, 256, 0, stream>>>(fcw, fwbf, 513, 512, 512);
  hbias_kernel<<<32768, 256, 0, stream>>>(h0, Whh, bih, bhh, hb);
  gemm1_kernel<<<8192, 256, 0, stream>>>(xbf, wpk, hb, c0, hn);
  gemm2_kernel<<<2560, 256, 0, stream>>>(hn, fwbf, fcb, out);
}

// Round 6
// 386.823 us; speedup vs baseline: 1.2193x; 1.0048x over previous
//
#include <hip/hip_runtime.h>
#include <hip/hip_bf16.h>
#include <stdint.h>

// ---------------------------------------------------------------------------
// Decoder (teacher-forced, state never advances):
//   gates = x @ W_ih^T + (h0 @ W_hh^T + b_ih + b_hh)  (broadcast over t)
//   i,f,g,o = split(gates); c' = sig(f)*c0 + sig(i)*tanh(g); h' = sig(o)*tanh(c')
//   out = h' @ fc_w^T + fc_b
// Sizes: B=64, T=1024, D=513, H=512, 4H=2048.  M = B*T = 65536.
// R5: per-wave tile 128x64 (42.7 flop/LDS-byte, lifts the LDS-BW cap from
//     67% to 89% MfmaUtil), block 256x128 / 4 waves, BK=32, triple-buffered
//     72KB LDS (2 blocks/CU), ONE barrier + counted vmcnt(6) per K-tile,
//     fragment-ordered 0-conflict LDS, setprio, XCD swizzle, gate-interleaved
//     W packing (lane-local LSTM epilogue).
// ---------------------------------------------------------------------------

typedef __bf16 bf16x8 __attribute__((ext_vector_type(8)));
typedef float f32x4 __attribute__((ext_vector_type(4)));

#define MFMA_BF16 __builtin_amdgcn_mfma_f32_16x16x32_bf16

__device__ __forceinline__ void gld16(const void* gptr, void* lptr) {
  __builtin_amdgcn_global_load_lds(
      (const __attribute__((address_space(1))) void*)gptr,
      (__attribute__((address_space(3))) void*)lptr, 16, 0, 0);
}

__device__ __forceinline__ float fsigm(float x) {
  x = fminf(fmaxf(x, -30.f), 30.f);
  return __frcp_rn(1.f + __expf(-x));
}
__device__ __forceinline__ float ftanh(float x) {
  x = fminf(fmaxf(x, -15.f), 15.f);
  const float e = __expf(2.f * x);
  return (e - 1.f) * __frcp_rn(e + 1.f);
}

// --------------------------- pack fp32 -> bf16 ------------------------------
__global__ void pack_bf16_kernel(const float* __restrict__ in,
                                 __bf16* __restrict__ out,
                                 int rows_in, int kin, int kout) {
  const int r = blockIdx.x;
  const bool rv = r < rows_in;
  for (int c = threadIdx.x * 2; c < kout; c += 512) {
    float v0 = (rv && c < kin) ? in[(size_t)r * kin + c] : 0.f;
    float v1 = (rv && c + 1 < kin) ? in[(size_t)r * kin + c + 1] : 0.f;
    union { __bf16 h[2]; uint32_t u; } p;
    p.h[0] = (__bf16)v0;
    p.h[1] = (__bf16)v1;
    *(uint32_t*)&out[(size_t)r * kout + c] = p.u;
  }
}

// pack W_ih gate-interleaved: packed row p -> gate (p>>4)&3, h (p>>6)*16+(p&15)
__global__ void pack_wih_kernel(const float* __restrict__ Wih,
                                __bf16* __restrict__ wpk) {
  const int p = blockIdx.x;  // 0..2047
  const int g = (p >> 4) & 3;
  const int h = ((p >> 6) << 4) + (p & 15);
  const float* src = Wih + (size_t)(g * 512 + h) * 513;
  for (int c = threadIdx.x * 2; c < 544; c += 512) {
    float v0 = (c < 513) ? src[c] : 0.f;
    float v1 = (c + 1 < 513) ? src[c + 1] : 0.f;
    union { __bf16 hh[2]; uint32_t u; } pk;
    pk.hh[0] = (__bf16)v0;
    pk.hh[1] = (__bf16)v1;
    *(uint32_t*)&wpk[(size_t)p * 544 + c] = pk.u;
  }
}

// --------------------------- hbias ------------------------------------------
__global__ void hbias_kernel(const float* __restrict__ h0,
                             const float* __restrict__ Whh,
                             const float* __restrict__ bih,
                             const float* __restrict__ bhh,
                             float* __restrict__ hbias) {
  const int t = threadIdx.x, w = t >> 6, l = t & 63;
  const int b = blockIdx.x >> 9;
  const int g = ((blockIdx.x & 511) << 2) | w;
  const float* hr = h0 + b * 512;
  const float* wr = Whh + (size_t)g * 512;
  float s = 0.f;
#pragma unroll
  for (int h = 0; h < 512; h += 64) s = fmaf(hr[h + l], wr[h + l], s);
#pragma unroll
  for (int off = 32; off; off >>= 1) s += __shfl_down(s, off);
  if (l == 0) hbias[b * 2048 + g] = s + bih[g] + bhh[g];
}

// --------------------------- triple-buffer GEMM core ------------------------
// Block tile 256x128, BK=32, 4 waves (2M x 2N), per-wave 128x64 (acc[8][4],
// 32 MFMA / 12 ds_read_b128 per K-tile). LDS: 3 buffers x (A 16KB + B 8KB)
// = 72KB. Tile kt reads buf kt%3, stages tile kt+2 into (kt+2)%3; one
// barrier/tile; steady-state gate vmcnt(6) (6 gld16/thread/tile in flight).
// Subtile = 16 rows x 32 k fragment-ordered: gld16 dest and ds_read are both
// identity (base + lane*16) -> 0 bank conflicts.
template <int NKT, int KSTR>
__device__ __forceinline__ void gemm_core(
    const __bf16* __restrict__ A, const __bf16* __restrict__ B,
    size_t m0, int n0, char* lds, f32x4 (&acc)[8][4],
    int w, int l, int wm, int wc) {
  const int lr = l & 15, lq = l >> 4;
  // wave w stages A subtiles {w,w+4,w+8,w+12}, B subtiles {w,w+4}.
  const __bf16* ag = A + (m0 + w * 16 + lr) * KSTR + lq * 8;
  const __bf16* bg = B + (size_t)(n0 + w * 16 + lr) * KSTR + lq * 8;
  const int sdst = w << 10;                  // wave-uniform LDS dest
  const int ra = (wm << 13) + l * 16;        // A read: subtile wm*8+mi
  const int rbB = 16384 + (wc << 12) + l * 16;  // B read: subtile wc*4+ni

  // prologue: stage K-tiles 0 and 1 into buffers 0 and 1
#pragma unroll
  for (int p = 0; p < 2; ++p) {
    char* base = lds + p * 24576;
#pragma unroll
    for (int i = 0; i < 4; ++i)
      gld16(ag + p * 32 + i * (64 * KSTR), base + sdst + i * 4096);
#pragma unroll
    for (int i = 0; i < 2; ++i)
      gld16(bg + p * 32 + i * (64 * KSTR), base + 16384 + sdst + i * 4096);
  }
  asm volatile("s_waitcnt vmcnt(6)" ::: "memory");  // tile-0 stage landed
  __builtin_amdgcn_s_barrier();

  int rb = 0;
  for (int kt = 0; kt < NKT; ++kt) {
    char* rbase = lds + rb * 24576;
    if (kt + 2 < NKT) {  // stage tile kt+2 into the buffer freed at kt-1
      char* wbase = lds + ((rb + 2) % 3) * 24576;
      const int kof = (kt + 2) * 32;
#pragma unroll
      for (int i = 0; i < 4; ++i)
        gld16(ag + kof + i * (64 * KSTR), wbase + sdst + i * 4096);
#pragma unroll
      for (int i = 0; i < 2; ++i)
        gld16(bg + kof + i * (64 * KSTR), wbase + 16384 + sdst + i * 4096);
    }
    bf16x8 af[8], bq[4];
#pragma unroll
    for (int i = 0; i < 8; ++i)
      af[i] = *(const bf16x8*)(rbase + ra + i * 1024);
#pragma unroll
    for (int i = 0; i < 4; ++i)
      bq[i] = *(const bf16x8*)(rbase + rbB + i * 1024);
    __builtin_amdgcn_s_setprio(1);
#pragma unroll
    for (int mi = 0; mi < 8; ++mi)
#pragma unroll
      for (int ni = 0; ni < 4; ++ni)
        acc[mi][ni] = MFMA_BF16(af[mi], bq[ni], acc[mi][ni], 0, 0, 0);
    __builtin_amdgcn_s_setprio(0);
    if (kt + 2 < NKT) {
      asm volatile("s_waitcnt vmcnt(6)" ::: "memory");  // tile kt+1 landed
    } else if (kt + 1 < NKT) {
      asm volatile("s_waitcnt vmcnt(0)" ::: "memory");  // tail: last tile
    }
    asm volatile("" ::: "memory");
    __builtin_amdgcn_s_barrier();
    rb = (rb == 2) ? 0 : rb + 1;
  }
}

// --------------------------- GEMM1 + LSTM cell ------------------------------
// A = xbf [65536 x 544], B = wpk [2048 x 544] gate-interleaved.
// grid 4096 = 256 m-tiles x 16 n-tiles.
__global__ __launch_bounds__(256, 2) void gemm1_kernel(
    const __bf16* __restrict__ xbf, const __bf16* __restrict__ wpk,
    const float* __restrict__ hbias, const float* __restrict__ c0,
    __bf16* __restrict__ hnew) {
  const int t = threadIdx.x, w = t >> 6, l = t & 63;
  const int wm = w >> 1, wc = w & 1;
  const int bid = blockIdx.x;
  const int swz = (bid & 7) * 512 + (bid >> 3);  // XCD-contiguous
  const size_t m0 = (size_t)(swz >> 4) << 8;
  const int n0 = (swz & 15) << 7;

  __shared__ __align__(16) char lds[73728];

  f32x4 acc[8][4];
#pragma unroll
  for (int mi = 0; mi < 8; ++mi)
#pragma unroll
    for (int ni = 0; ni < 4; ++ni) acc[mi][ni] = (f32x4){0.f, 0.f, 0.f, 0.f};

  gemm_core<17, 544>(xbf, wpk, m0, n0, lds, acc, w, l, wm, wc);

  // lane's packed col p = n0 + wc*64 + ni*16 + (l&15) -> gate = ni,
  // h = (n0/64 + wc)*16 + (l&15). All 4 gates lane-local.
  const int lr = l & 15, lq = l >> 4;
  const int hcol = (((n0 >> 6) + wc) << 4) + lr;
  const int b = (int)(m0 >> 10);
  const float hb0 = hbias[b * 2048 + hcol];
  const float hb1 = hbias[b * 2048 + 512 + hcol];
  const float hb2 = hbias[b * 2048 + 1024 + hcol];
  const float hb3 = hbias[b * 2048 + 1536 + hcol];
  const float c0v = c0[b * 512 + hcol];
#pragma unroll
  for (int mi = 0; mi < 8; ++mi) {
#pragma unroll
    for (int r = 0; r < 4; ++r) {
      const size_t m = m0 + wm * 128 + mi * 16 + lq * 4 + r;
      const float gi = acc[mi][0][r] + hb0;
      const float gf = acc[mi][1][r] + hb1;
      const float gg = acc[mi][2][r] + hb2;
      const float go = acc[mi][3][r] + hb3;
      const float cn = fsigm(gf) * c0v + fsigm(gi) * ftanh(gg);
      hnew[m * 512 + hcol] = (__bf16)(fsigm(go) * ftanh(cn));
    }
  }
}

// --------------------------- GEMM2 + bias -----------------------------------
// A = hnew [65536 x 512], B = fwbf [640 x 512] (rows 513.. zero).
// grid 1280 = 256 m-tiles x 5 n-tiles.
__global__ __launch_bounds__(256, 2) void gemm2_kernel(
    const __bf16* __restrict__ hnew, const __bf16* __restrict__ fcw,
    const float* __restrict__ fcb, float* __restrict__ out) {
  const int t = threadIdx.x, w = t >> 6, l = t & 63;
  const int wm = w >> 1, wc = w & 1;
  const int bid = blockIdx.x;
  const int swz = (bid & 7) * 160 + (bid >> 3);
  const size_t m0 = (size_t)(swz / 5) << 8;
  const int n0 = (swz % 5) << 7;

  __shared__ __align__(16) char lds[73728];

  f32x4 acc[8][4];
#pragma unroll
  for (int mi = 0; mi < 8; ++mi)
#pragma unroll
    for (int ni = 0; ni < 4; ++ni) acc[mi][ni] = (f32x4){0.f, 0.f, 0.f, 0.f};

  gemm_core<16, 512>(hnew, fcw, m0, n0, lds, acc, w, l, wm, wc);

  const int lr = l & 15, lq = l >> 4;
#pragma unroll
  for (int ni = 0; ni < 4; ++ni) {
    const int n = n0 + wc * 64 + ni * 16 + lr;
    if (n < 513) {
      const float bias = fcb[n];
#pragma unroll
      for (int mi = 0; mi < 8; ++mi) {
#pragma unroll
        for (int r = 0; r < 4; ++r) {
          const size_t m = m0 + wm * 128 + mi * 16 + lq * 4 + r;
          out[m * 513 + n] = acc[mi][ni][r] + bias;
        }
      }
    }
  }
}

// --------------------------- launch -----------------------------------------
extern "C" void kernel_launch(void* const* d_in, const int* in_sizes, int n_in,
                              void* d_out, int out_size, void* d_ws, size_t ws_size,
                              hipStream_t stream) {
  const float* x = (const float*)d_in[0];     // [64,1024,513]
  const float* h0 = (const float*)d_in[1];    // [1,64,512]
  const float* c0 = (const float*)d_in[2];    // [1,64,512]
  const float* Wih = (const float*)d_in[3];   // [2048,513]
  const float* Whh = (const float*)d_in[4];   // [2048,512]
  const float* bih = (const float*)d_in[5];   // [2048]
  const float* bhh = (const float*)d_in[6];   // [2048]
  const float* fcw = (const float*)d_in[7];   // [513,512]
  const float* fcb = (const float*)d_in[8];   // [513]
  float* out = (float*)d_out;                 // [64,1024,513]

  char* ws = (char*)d_ws;
  __bf16* xbf = (__bf16*)(ws);                 // 65536*544*2 = 71,303,168
  __bf16* wpk = (__bf16*)(ws + 71303168);      //  2048*544*2 =  2,228,224
  __bf16* fwbf = (__bf16*)(ws + 73531392);     //   640*512*2 =    655,360
  float* hb = (float*)(ws + 74186752);         //   64*2048*4 =    524,288
  __bf16* hn = (__bf16*)(ws + 74711040);       // 65536*512*2 = 67,108,864
  // total ws use: 141,819,904 bytes

  pack_bf16_kernel<<<65536, 256, 0, stream>>>(x, xbf, 65536, 513, 544);
  pack_wih_kernel<<<2048, 256, 0, stream>>>(Wih, wpk);
  pack_bf16_kernel<<<640, 256, 0, stream>>>(fcw, fwbf, 513, 512, 512);
  hbias_kernel<<<32768, 256, 0, stream>>>(h0, Whh, bih, bhh, hb);
  gemm1_kernel<<<4096, 256, 0, stream>>>(xbf, wpk, hb, c0, hn);
  gemm2_kernel<<<1280, 256, 0, stream>>>(hn, fwbf, fcb, out);
}

// Round 7
// 381.653 us; speedup vs baseline: 1.2358x; 1.0135x over previous
//
#include <hip/hip_runtime.h>
#include <hip/hip_bf16.h>
#include <stdint.h>

// ---------------------------------------------------------------------------
// Decoder (teacher-forced, state never advances):
//   gates = x @ W_ih^T + (h0 @ W_hh^T + b_ih + b_hh)  (broadcast over t)
//   i,f,g,o = split(gates); c' = sig(f)*c0 + sig(i)*tanh(g); h' = sig(o)*tanh(c')
//   out = h' @ fc_w^T + fc_b
// Sizes: B=64, T=1024, D=513, H=512, 4H=2048.  M = B*T = 65536.
// R6: occupancy play. 512-thr blocks (8 waves, 4Mx2N), tile 256x128, BK=32,
//     per-wave 64x64 (acc[4][4]), triple-buffered 72KB LDS -> 2 blocks/CU
//     = 16 waves/CU with __launch_bounds__(512,4) (<=128 regs/wave).
//     3 gld16/thread/K-tile, ONE barrier + counted vmcnt(3) per K-tile
//     (vmcnt(0) only at tail). Fragment-ordered 0-conflict LDS, setprio,
//     XCD swizzle, gate-interleaved W packing (lane-local LSTM epilogue).
// ---------------------------------------------------------------------------

typedef __bf16 bf16x8 __attribute__((ext_vector_type(8)));
typedef float f32x4 __attribute__((ext_vector_type(4)));

#define MFMA_BF16 __builtin_amdgcn_mfma_f32_16x16x32_bf16

__device__ __forceinline__ void gld16(const void* gptr, void* lptr) {
  __builtin_amdgcn_global_load_lds(
      (const __attribute__((address_space(1))) void*)gptr,
      (__attribute__((address_space(3))) void*)lptr, 16, 0, 0);
}

__device__ __forceinline__ float fsigm(float x) {
  x = fminf(fmaxf(x, -30.f), 30.f);
  return __frcp_rn(1.f + __expf(-x));
}
__device__ __forceinline__ float ftanh(float x) {
  x = fminf(fmaxf(x, -15.f), 15.f);
  const float e = __expf(2.f * x);
  return (e - 1.f) * __frcp_rn(e + 1.f);
}

// --------------------------- pack fp32 -> bf16 ------------------------------
__global__ void pack_bf16_kernel(const float* __restrict__ in,
                                 __bf16* __restrict__ out,
                                 int rows_in, int kin, int kout) {
  const int r = blockIdx.x;
  const bool rv = r < rows_in;
  for (int c = threadIdx.x * 2; c < kout; c += 512) {
    float v0 = (rv && c < kin) ? in[(size_t)r * kin + c] : 0.f;
    float v1 = (rv && c + 1 < kin) ? in[(size_t)r * kin + c + 1] : 0.f;
    union { __bf16 h[2]; uint32_t u; } p;
    p.h[0] = (__bf16)v0;
    p.h[1] = (__bf16)v1;
    *(uint32_t*)&out[(size_t)r * kout + c] = p.u;
  }
}

// pack W_ih gate-interleaved: packed row p -> gate (p>>4)&3, h (p>>6)*16+(p&15)
__global__ void pack_wih_kernel(const float* __restrict__ Wih,
                                __bf16* __restrict__ wpk) {
  const int p = blockIdx.x;  // 0..2047
  const int g = (p >> 4) & 3;
  const int h = ((p >> 6) << 4) + (p & 15);
  const float* src = Wih + (size_t)(g * 512 + h) * 513;
  for (int c = threadIdx.x * 2; c < 544; c += 512) {
    float v0 = (c < 513) ? src[c] : 0.f;
    float v1 = (c + 1 < 513) ? src[c + 1] : 0.f;
    union { __bf16 hh[2]; uint32_t u; } pk;
    pk.hh[0] = (__bf16)v0;
    pk.hh[1] = (__bf16)v1;
    *(uint32_t*)&wpk[(size_t)p * 544 + c] = pk.u;
  }
}

// --------------------------- hbias ------------------------------------------
__global__ void hbias_kernel(const float* __restrict__ h0,
                             const float* __restrict__ Whh,
                             const float* __restrict__ bih,
                             const float* __restrict__ bhh,
                             float* __restrict__ hbias) {
  const int t = threadIdx.x, w = t >> 6, l = t & 63;
  const int b = blockIdx.x >> 9;
  const int g = ((blockIdx.x & 511) << 2) | w;
  const float* hr = h0 + b * 512;
  const float* wr = Whh + (size_t)g * 512;
  float s = 0.f;
#pragma unroll
  for (int h = 0; h < 512; h += 64) s = fmaf(hr[h + l], wr[h + l], s);
#pragma unroll
  for (int off = 32; off; off >>= 1) s += __shfl_down(s, off);
  if (l == 0) hbias[b * 2048 + g] = s + bih[g] + bhh[g];
}

// --------------------------- triple-buffer GEMM core ------------------------
// Block tile 256x128, BK=32, 8 waves (4M x 2N), per-wave 64x64 (acc[4][4],
// 16 MFMA / 8 ds_read_b128 per K-tile). LDS: 3 buffers x (A 16KB + B 8KB)
// = 72KB. Tile kt reads buf kt%3, stages tile kt+2 into (kt+2)%3; one
// barrier/tile; steady-state gate vmcnt(3) (3 gld16/thread/tile in flight).
// Subtile = 16 rows x 32 k fragment-ordered: gld16 dest and ds_read are both
// identity (base + lane*16) -> 0 bank conflicts.
// A: wave wid stages subtiles {wid, wid+8}; B: wave wid stages subtile wid.
template <int NKT, int KSTR>
__device__ __forceinline__ void gemm_core(
    const __bf16* __restrict__ A, const __bf16* __restrict__ B,
    size_t m0, int n0, char* lds, f32x4 (&acc)[4][4],
    int wid, int l, int wm, int wc) {
  const int lr = l & 15, lq = l >> 4;
  const __bf16* ag = A + (m0 + wid * 16 + lr) * KSTR + lq * 8;
  const __bf16* bg = B + (size_t)(n0 + wid * 16 + lr) * KSTR + lq * 8;
  const int sdA = wid << 10;                    // A subtile wid (+8192: wid+8)
  const int sdB = 16384 + (wid << 10);          // B subtile wid
  const int ra = (wm << 12) + l * 16;           // A read: subtile wm*4+mi
  const int rbB = 16384 + (wc << 12) + l * 16;  // B read: subtile wc*4+ni

  // prologue: stage K-tiles 0 and 1 into buffers 0 and 1
#pragma unroll
  for (int p = 0; p < 2; ++p) {
    char* base = lds + p * 24576;
    gld16(ag + p * 32, base + sdA);
    gld16(ag + p * 32 + 128 * KSTR, base + sdA + 8192);
    gld16(bg + p * 32, base + sdB);
  }
  asm volatile("s_waitcnt vmcnt(3)" ::: "memory");  // tile-0 stage landed
  __builtin_amdgcn_s_barrier();

  int rb = 0;
  for (int kt = 0; kt < NKT; ++kt) {
    char* rbase = lds + rb * 24576;
    if (kt + 2 < NKT) {  // stage tile kt+2 into the buffer freed at kt-1
      char* wbase = lds + ((rb + 2) % 3) * 24576;
      const int kof = (kt + 2) * 32;
      gld16(ag + kof, wbase + sdA);
      gld16(ag + kof + 128 * KSTR, wbase + sdA + 8192);
      gld16(bg + kof, wbase + sdB);
    }
    bf16x8 af[4], bq[4];
#pragma unroll
    for (int i = 0; i < 4; ++i)
      af[i] = *(const bf16x8*)(rbase + ra + i * 1024);
#pragma unroll
    for (int i = 0; i < 4; ++i)
      bq[i] = *(const bf16x8*)(rbase + rbB + i * 1024);
    __builtin_amdgcn_s_setprio(1);
#pragma unroll
    for (int mi = 0; mi < 4; ++mi)
#pragma unroll
      for (int ni = 0; ni < 4; ++ni)
        acc[mi][ni] = MFMA_BF16(af[mi], bq[ni], acc[mi][ni], 0, 0, 0);
    __builtin_amdgcn_s_setprio(0);
    if (kt + 2 < NKT) {
      asm volatile("s_waitcnt vmcnt(3)" ::: "memory");  // tile kt+1 landed
    } else if (kt + 1 < NKT) {
      asm volatile("s_waitcnt vmcnt(0)" ::: "memory");  // tail: last tile
    }
    asm volatile("" ::: "memory");
    __builtin_amdgcn_s_barrier();
    rb = (rb == 2) ? 0 : rb + 1;
  }
}

// --------------------------- GEMM1 + LSTM cell ------------------------------
// A = xbf [65536 x 544], B = wpk [2048 x 544] gate-interleaved.
// grid 4096 = 256 m-tiles x 16 n-tiles.
__global__ __launch_bounds__(512, 4) void gemm1_kernel(
    const __bf16* __restrict__ xbf, const __bf16* __restrict__ wpk,
    const float* __restrict__ hbias, const float* __restrict__ c0,
    __bf16* __restrict__ hnew) {
  const int t = threadIdx.x, wid = t >> 6, l = t & 63;
  const int wm = wid >> 1, wc = wid & 1;
  const int bid = blockIdx.x;
  const int swz = (bid & 7) * 512 + (bid >> 3);  // XCD-contiguous
  const size_t m0 = (size_t)(swz >> 4) << 8;
  const int n0 = (swz & 15) << 7;

  __shared__ __align__(16) char lds[73728];

  f32x4 acc[4][4];
#pragma unroll
  for (int mi = 0; mi < 4; ++mi)
#pragma unroll
    for (int ni = 0; ni < 4; ++ni) acc[mi][ni] = (f32x4){0.f, 0.f, 0.f, 0.f};

  gemm_core<17, 544>(xbf, wpk, m0, n0, lds, acc, wid, l, wm, wc);

  // lane's packed col p = n0 + wc*64 + ni*16 + (l&15) -> gate = ni,
  // h = (n0/64 + wc)*16 + (l&15). All 4 gates lane-local.
  const int lr = l & 15, lq = l >> 4;
  const int hcol = (((n0 >> 6) + wc) << 4) + lr;
  const int b = (int)(m0 >> 10);
  const float hb0 = hbias[b * 2048 + hcol];
  const float hb1 = hbias[b * 2048 + 512 + hcol];
  const float hb2 = hbias[b * 2048 + 1024 + hcol];
  const float hb3 = hbias[b * 2048 + 1536 + hcol];
  const float c0v = c0[b * 512 + hcol];
#pragma unroll
  for (int mi = 0; mi < 4; ++mi) {
#pragma unroll
    for (int r = 0; r < 4; ++r) {
      const size_t m = m0 + wm * 64 + mi * 16 + lq * 4 + r;
      const float gi = acc[mi][0][r] + hb0;
      const float gf = acc[mi][1][r] + hb1;
      const float gg = acc[mi][2][r] + hb2;
      const float go = acc[mi][3][r] + hb3;
      const float cn = fsigm(gf) * c0v + fsigm(gi) * ftanh(gg);
      hnew[m * 512 + hcol] = (__bf16)(fsigm(go) * ftanh(cn));
    }
  }
}

// --------------------------- GEMM2 + bias -----------------------------------
// A = hnew [65536 x 512], B = fwbf [640 x 512] (rows 513.. zero).
// grid 1280 = 256 m-tiles x 5 n-tiles.
__global__ __launch_bounds__(512, 4) void gemm2_kernel(
    const __bf16* __restrict__ hnew, const __bf16* __restrict__ fcw,
    const float* __restrict__ fcb, float* __restrict__ out) {
  const int t = threadIdx.x, wid = t >> 6, l = t & 63;
  const int wm = wid >> 1, wc = wid & 1;
  const int bid = blockIdx.x;
  const int swz = (bid & 7) * 160 + (bid >> 3);
  const size_t m0 = (size_t)(swz / 5) << 8;
  const int n0 = (swz % 5) << 7;

  __shared__ __align__(16) char lds[73728];

  f32x4 acc[4][4];
#pragma unroll
  for (int mi = 0; mi < 4; ++mi)
#pragma unroll
    for (int ni = 0; ni < 4; ++ni) acc[mi][ni] = (f32x4){0.f, 0.f, 0.f, 0.f};

  gemm_core<16, 512>(hnew, fcw, m0, n0, lds, acc, wid, l, wm, wc);

  const int lr = l & 15, lq = l >> 4;
#pragma unroll
  for (int ni = 0; ni < 4; ++ni) {
    const int n = n0 + wc * 64 + ni * 16 + lr;
    if (n < 513) {
      const float bias = fcb[n];
#pragma unroll
      for (int mi = 0; mi < 4; ++mi) {
#pragma unroll
        for (int r = 0; r < 4; ++r) {
          const size_t m = m0 + wm * 64 + mi * 16 + lq * 4 + r;
          out[m * 513 + n] = acc[mi][ni][r] + bias;
        }
      }
    }
  }
}

// --------------------------- launch -----------------------------------------
extern "C" void kernel_launch(void* const* d_in, const int* in_sizes, int n_in,
                              void* d_out, int out_size, void* d_ws, size_t ws_size,
                              hipStream_t stream) {
  const float* x = (const float*)d_in[0];     // [64,1024,513]
  const float* h0 = (const float*)d_in[1];    // [1,64,512]
  const float* c0 = (const float*)d_in[2];    // [1,64,512]
  const float* Wih = (const float*)d_in[3];   // [2048,513]
  const float* Whh = (const float*)d_in[4];   // [2048,512]
  const float* bih = (const float*)d_in[5];   // [2048]
  const float* bhh = (const float*)d_in[6];   // [2048]
  const float* fcw = (const float*)d_in[7];   // [513,512]
  const float* fcb = (const float*)d_in[8];   // [513]
  float* out = (float*)d_out;                 // [64,1024,513]

  char* ws = (char*)d_ws;
  __bf16* xbf = (__bf16*)(ws);                 // 65536*544*2 = 71,303,168
  __bf16* wpk = (__bf16*)(ws + 71303168);      //  2048*544*2 =  2,228,224
  __bf16* fwbf = (__bf16*)(ws + 73531392);     //   640*512*2 =    655,360
  float* hb = (float*)(ws + 74186752);         //   64*2048*4 =    524,288
  __bf16* hn = (__bf16*)(ws + 74711040);       // 65536*512*2 = 67,108,864
  // total ws use: 141,819,904 bytes

  pack_bf16_kernel<<<65536, 256, 0, stream>>>(x, xbf, 65536, 513, 544);
  pack_wih_kernel<<<2048, 256, 0, stream>>>(Wih, wpk);
  pack_bf16_kernel<<<640, 256, 0, stream>>>(fcw, fwbf, 513, 512, 512);
  hbias_kernel<<<32768, 256, 0, stream>>>(h0, Whh, bih, bhh, hb);
  gemm1_kernel<<<4096, 512, 0, stream>>>(xbf, wpk, hb, c0, hn);
  gemm2_kernel<<<1280, 512, 0, stream>>>(hn, fwbf, fcb, out);
}